// Round 5
// baseline (193.451 us; speedup 1.0000x reference)
//
#include <hip/hip_runtime.h>

#define Bb 4
#define Ll 256
#define NEG 0.2f

typedef __attribute__((ext_vector_type(8))) short short8;
typedef __attribute__((ext_vector_type(4))) float f32x4;
typedef __attribute__((ext_vector_type(4))) unsigned uint4v;

__device__ __forceinline__ float lrelu(float x) { return x >= 0.f ? x : NEG * x; }

__device__ __forceinline__ short f2bf(float x) {
  unsigned u = __builtin_bit_cast(unsigned, x);
  unsigned r = (u + 0x7FFFu + ((u >> 16) & 1u)) >> 16;
  return (short)r;
}

// pack two f32 -> u32 of 2 bf16 (round half up)
__device__ __forceinline__ unsigned pack2bf(float e, float o) {
  unsigned ue = __builtin_bit_cast(unsigned, e);
  unsigned uo = __builtin_bit_cast(unsigned, o);
  return ((ue + 0x8000u) >> 16) | ((uo + 0x8000u) & 0xFFFF0000u);
}

// ---------------- merged prep: blocks 0..127 -> Gt (linear bf16 [n][k]);
// block 128 -> Vbf (bf16 [16][128], rows 8..15 zero), ch(8), c0(128) ----------------
__global__ void prep_kernel(const float* We_w, const float* We_b, const float* attn_w,
                            const float* We2_w, const float* We2_b, const float* edge_w,
                            const float* edge_b, const float* out_e_w, const float* out_e_b,
                            short* Vbf, float* chg, float* c0g, short* Gt) {
  int blk = blockIdx.x;
  int t = threadIdx.x; // 128 threads
  if (blk < 128) {
    __shared__ float m2[128];
    int c = blk; // k index
    int h = t >> 4, e = t & 15;
    float s = 0.f;
    for (int d = 0; d < 16; ++d) s += We2_w[c * 128 + h * 16 + d] * edge_w[d * 16 + e];
    m2[t] = s;
    __syncthreads();
    float g = 0.f;
    for (int f = 0; f < 128; ++f) g += m2[f] * out_e_w[f * 128 + t];
    Gt[t * 128 + c] = f2bf(g);
  } else {
    __shared__ float b2e[128];
    const float* we = attn_w + 64;
    for (int idx = t; idx < 1024; idx += 128) {
      int c = idx >> 3, h = idx & 7;
      float s = 0.f;
      for (int d = 0; d < 16; ++d) s += We_w[c * 128 + h * 16 + d] * we[d];
      Vbf[h * 128 + c] = f2bf(s);
      Vbf[(h + 8) * 128 + c] = 0;
    }
    if (t < 8) {
      float s = 0.f;
      for (int d = 0; d < 16; ++d) s += We_b[t * 16 + d] * we[d];
      chg[t] = s;
    }
    {
      int h = t >> 4, e = t & 15;
      float s = 0.f;
      for (int d = 0; d < 16; ++d) s += We2_b[h * 16 + d] * edge_w[d * 16 + e];
      b2e[t] = s + edge_b[e];
    }
    __syncthreads();
    float s = out_e_b[t];
    for (int f = 0; f < 128; ++f) s += b2e[f] * out_e_w[f * 128 + t];
    c0g[t] = s;
  }
}

// ---------------- pass A: stream edge -> bf16 image (ebf) + se via MFMA ----------------
// 1024 blocks = one (b,i) slab of 256 rows each; 4 waves x 4 row-tiles.
template <bool WE>
__global__ __launch_bounds__(256) void pass_a(const float* __restrict__ edge,
                                              const short* __restrict__ Vbf,
                                              const float* __restrict__ chg,
                                              short* __restrict__ ebf,
                                              float* __restrict__ seg) {
  int t = threadIdx.x;
  int l = t & 63, w = t >> 6;
  int lc = l & 15, lq = l >> 4;
  long slab = blockIdx.x;
  const float* ebase = edge + slab * 32768;

  short8 vb[4];
#pragma unroll
  for (int ks = 0; ks < 4; ++ks) vb[ks] = *(const short8*)(Vbf + lc * 128 + ks * 32 + lq * 8);

  f32x4 acc[4];
#pragma unroll
  for (int mf = 0; mf < 4; ++mf) acc[mf] = (f32x4){0.f, 0.f, 0.f, 0.f};

#pragma unroll
  for (int mf = 0; mf < 4; ++mf) {
    int row = w * 64 + mf * 16 + lc;
    const float* ap = ebase + row * 128 + lq * 8;
    float4 f[8];
#pragma unroll
    for (int ks = 0; ks < 4; ++ks) {
      f[2 * ks] = *(const float4*)(ap + ks * 32);
      f[2 * ks + 1] = *(const float4*)(ap + ks * 32 + 4);
    }
#pragma unroll
    for (int ks = 0; ks < 4; ++ks) {
      uint4v u;
      u.x = pack2bf(f[2 * ks].x, f[2 * ks].y);
      u.y = pack2bf(f[2 * ks].z, f[2 * ks].w);
      u.z = pack2bf(f[2 * ks + 1].x, f[2 * ks + 1].y);
      u.w = pack2bf(f[2 * ks + 1].z, f[2 * ks + 1].w);
      if constexpr (WE) *(uint4v*)(ebf + slab * 32768 + row * 128 + ks * 32 + lq * 8) = u;
      acc[mf] = __builtin_amdgcn_mfma_f32_16x16x32_bf16(vb[ks], __builtin_bit_cast(short8, u),
                                                        acc[mf], 0, 0, 0);
    }
  }
  // acc[mf][r]: se[row = w*64+mf*16+lc][head = lq*4+r], valid for lq<2
  if (lq < 2) {
    f32x4 chv = *(const f32x4*)(chg + lq * 4);
#pragma unroll
    for (int mf = 0; mf < 4; ++mf) {
      int row = w * 64 + mf * 16 + lc;
      f32x4 v = acc[mf] + chv;
      *(f32x4*)(seg + slab * 2048 + row * 8 + lq * 4) = v;
    }
  }
}

// ---------------- node_in_fused: node_p = node@Wn + b; Whh; si; sj ----------------
__global__ __launch_bounds__(256) void node_in_fused(
    const float* __restrict__ node, const float* __restrict__ Wn_w,
    const float* __restrict__ Wn_b, const float* __restrict__ Wh_w,
    const float* __restrict__ Wh_b, const float* __restrict__ attn_w,
    float* __restrict__ node_p, float* __restrict__ Whh, float* __restrict__ si,
    float* __restrict__ sj) {
  __shared__ float a[4][256];
  __shared__ float np[4][256];
  int t = threadIdx.x;
  int row0 = blockIdx.x * 4;
  for (int q = t; q < 1024; q += 256) a[q >> 8][q & 255] = node[(long)row0 * 256 + q];
  __syncthreads();
  float acc[4];
  float bvv = Wn_b[t];
#pragma unroll
  for (int r = 0; r < 4; ++r) acc[r] = bvv;
  for (int k = 0; k < 256; ++k) {
    float w = Wn_w[k * 256 + t];
#pragma unroll
    for (int r = 0; r < 4; ++r) acc[r] += a[r][k] * w;
  }
#pragma unroll
  for (int r = 0; r < 4; ++r) {
    node_p[(long)(row0 + r) * 256 + t] = acc[r];
    np[r][t] = acc[r];
  }
  __syncthreads();
  int h = t >> 5, e = t & 31;
  float wb2 = Wh_b[e];
#pragma unroll
  for (int r = 0; r < 4; ++r) {
    float s = wb2;
    for (int d = 0; d < 32; ++d) s += np[r][h * 32 + d] * Wh_w[d * 32 + e];
    Whh[(long)(row0 + r) * 256 + t] = s;
  }
  if (t < 64) {
    int r = t >> 4, idx = t & 15, hh = idx & 7;
    const float* w = attn_w + (idx < 8 ? 0 : 32);
    float s = 0.f;
    for (int d = 0; d < 32; ++d) s += np[r][hh * 32 + d] * w[d];
    ((idx < 8) ? si : sj)[(long)(row0 + r) * 8 + hh] = s;
  }
}

// ---------------- attn_fused v2: softmax + agg -> node_h ----------------
__global__ __launch_bounds__(256) void attn_fused(
    const float* __restrict__ node_p, const float* __restrict__ Whh,
    const float* __restrict__ si, const float* __restrict__ sj,
    const float* __restrict__ seg, float* __restrict__ node_h) {
  __shared__ float sjl[2048];
  __shared__ float sel[2048];
  __shared__ float pl[2048];
  __shared__ float sil[8];
  int t = threadIdx.x, bi = blockIdx.x;
  int b = bi >> 8, i = bi & 255;
  for (int q = t; q < 2048; q += 256) sjl[q] = sj[(long)b * 2048 + q];
  for (int q = t; q < 2048; q += 256) sel[q] = seg[(long)bi * 2048 + q];
  if (t < 8) sil[t] = si[(long)bi * 8 + t];
  __syncthreads();

  int g = t >> 5, l32 = t & 31;
  float sc[8];
  float mx = -1e30f;
#pragma unroll
  for (int m = 0; m < 8; ++m) {
    int k = l32 + 32 * m;
    float v = -1e30f;
    if (k < 255) {
      int jj = k + (k >= i ? 1 : 0);
      v = sil[g] + sjl[jj * 8 + g] + sel[jj * 8 + g];
      v = lrelu(v);
    }
    sc[m] = v;
    mx = fmaxf(mx, v);
  }
#pragma unroll
  for (int d = 16; d >= 1; d >>= 1) mx = fmaxf(mx, __shfl_xor(mx, d));
  float sum = 0.f;
#pragma unroll
  for (int m = 0; m < 8; ++m) {
    int k = l32 + 32 * m;
    float e = (k < 255) ? __expf(sc[m] - mx) : 0.f;
    sc[m] = e;
    sum += e;
  }
#pragma unroll
  for (int d = 16; d >= 1; d >>= 1) sum += __shfl_xor(sum, d);
  float inv = 1.f / sum;
#pragma unroll
  for (int m = 0; m < 8; ++m) {
    int k = l32 + 32 * m;
    if (k < 255) pl[k * 8 + g] = sc[m] * inv;
  }
  __syncthreads();

  int h = g;
  const float* wb = Whh + (long)b * 65536 + t;
  float acc0 = 0.f, acc1 = 0.f;
#pragma unroll 8
  for (int j = 0; j < 256; j += 2) {
    int k0 = (j == 0) ? 254 : (j - 1);
    int k1 = j;
    float w0 = (j == i) ? 0.f : pl[k0 * 8 + h];
    float w1 = (j + 1 == i) ? 0.f : pl[k1 * 8 + h];
    acc0 += w0 * wb[(long)j * 256];
    acc1 += w1 * wb[(long)(j + 1) * 256];
  }
  float acc = acc0 + acc1;
  float np = node_p[(long)bi * 256 + t];
  node_h[(long)bi * 256 + t] = np + lrelu(acc);
}

// ---------------- node_out_pq: out_node; node_p2; P/Q ----------------
__global__ __launch_bounds__(256) void node_out_pq(
    const float* __restrict__ node_h, const float* __restrict__ out_n_w,
    const float* __restrict__ out_n_b, const float* __restrict__ Wn2_w,
    const float* __restrict__ Wn2_b, const float* __restrict__ edge_w,
    const float* __restrict__ out_e_w, float* __restrict__ out_node,
    float* __restrict__ Pg, float* __restrict__ Qg) {
  __shared__ float a[4][256];
  __shared__ float b2[4][256];
  __shared__ float ninj[4][256];
  int t = threadIdx.x;
  int row0 = blockIdx.x * 4;
  for (int q = t; q < 1024; q += 256) a[q >> 8][q & 255] = node_h[(long)row0 * 256 + q];
  __syncthreads();
  float acc[4];
  float bv1 = out_n_b[t];
#pragma unroll
  for (int r = 0; r < 4; ++r) acc[r] = bv1;
  for (int k = 0; k < 256; ++k) {
    float w = out_n_w[k * 256 + t];
#pragma unroll
    for (int r = 0; r < 4; ++r) acc[r] += a[r][k] * w;
  }
#pragma unroll
  for (int r = 0; r < 4; ++r) {
    out_node[(long)(row0 + r) * 256 + t] = acc[r];
    b2[r][t] = acc[r];
  }
  __syncthreads();
  float acc2[4];
  float bv2 = Wn2_b[t];
#pragma unroll
  for (int r = 0; r < 4; ++r) acc2[r] = bv2;
  for (int k = 0; k < 256; ++k) {
    float w = Wn2_w[k * 256 + t];
#pragma unroll
    for (int r = 0; r < 4; ++r) acc2[r] += b2[r][k] * w;
  }
#pragma unroll
  for (int r = 0; r < 4; ++r) a[r][t] = acc2[r]; // node_p2
  __syncthreads();
  {
    int f = t & 127, h = f >> 4, e = f & 15;
    const float* w = edge_w + 256 + (t >> 7) * 512; // w_i / w_j
#pragma unroll
    for (int r = 0; r < 4; ++r) {
      float s = 0.f;
      for (int d = 0; d < 32; ++d) s += a[r][h * 32 + d] * w[d * 16 + e];
      ninj[r][t] = s;
    }
  }
  __syncthreads();
  {
    int o = t & 127;
    int half = (t >> 7) * 128;
#pragma unroll
    for (int r = 0; r < 4; ++r) {
      float s = 0.f;
      const float* src = ninj[r] + half;
      for (int f = 0; f < 128; ++f) s += src[f] * out_e_w[f * 128 + o];
      ((t < 128) ? Pg : Qg)[(long)(row0 + r) * 128 + o] = s;
    }
  }
}

// ---------------- pass C (MFMA, barrier-free streaming) ----------------
template <bool UE>
__global__ __launch_bounds__(256) void edge_out_kernel(
    const float* __restrict__ edge, const short* __restrict__ ebf,
    const short* __restrict__ Gt, const float* __restrict__ Pg,
    const float* __restrict__ Qg, const float* __restrict__ c0g,
    const float* __restrict__ oeb, float* __restrict__ out_edge) {
  int t = threadIdx.x;
  int l = t & 63, wid = t >> 6;
  int wm = wid >> 1, wn = wid & 1;
  int lc = l & 15, lq = l >> 4;

  long row0 = (long)blockIdx.x * 128;
  int b = (int)(row0 >> 16);
  int i = (int)((row0 >> 8) & 255);
  int j0 = (int)(row0 & 255);

  short8 bv[4][4];
#pragma unroll
  for (int ks = 0; ks < 4; ++ks)
#pragma unroll
    for (int nf = 0; nf < 4; ++nf)
      bv[ks][nf] = *(const short8*)(Gt + (wn * 64 + nf * 16 + lc) * 128 + ks * 32 + lq * 8);

  f32x4 acc[4][4];
#pragma unroll
  for (int mf = 0; mf < 4; ++mf)
#pragma unroll
    for (int nf = 0; nf < 4; ++nf) acc[mf][nf] = (f32x4){0.f, 0.f, 0.f, 0.f};

#pragma unroll
  for (int ks = 0; ks < 4; ++ks) {
    short8 av[4];
#pragma unroll
    for (int mf = 0; mf < 4; ++mf) {
      long row = row0 + wm * 64 + mf * 16 + lc;
      if constexpr (UE) {
        av[mf] = *(const short8*)(ebf + row * 128 + ks * 32 + lq * 8);
      } else {
        const float* ap = edge + row * 128 + ks * 32 + lq * 8;
        float4 f0 = *(const float4*)ap;
        float4 f1 = *(const float4*)(ap + 4);
        uint4v u;
        u.x = pack2bf(f0.x, f0.y);
        u.y = pack2bf(f0.z, f0.w);
        u.z = pack2bf(f1.x, f1.y);
        u.w = pack2bf(f1.z, f1.w);
        av[mf] = __builtin_bit_cast(short8, u);
      }
    }
#pragma unroll
    for (int mf = 0; mf < 4; ++mf)
#pragma unroll
      for (int nf = 0; nf < 4; ++nf)
        acc[mf][nf] =
            __builtin_amdgcn_mfma_f32_16x16x32_bf16(bv[ks][nf], av[mf], acc[mf][nf], 0, 0, 0);
  }

  f32x4 pc[4];
#pragma unroll
  for (int nf = 0; nf < 4; ++nf) {
    int cb = wn * 64 + nf * 16 + lq * 4;
    f32x4 p = *(const f32x4*)(Pg + ((long)(b * 256 + i)) * 128 + cb);
    f32x4 c0 = *(const f32x4*)(c0g + cb);
    pc[nf] = p + c0;
  }
#pragma unroll
  for (int mf = 0; mf < 4; ++mf) {
    int er = wm * 64 + mf * 16 + lc;
    int j = j0 + er;
    const float* Qrow = Qg + ((long)(b * 256 + j)) * 128;
    float* orow = out_edge + (row0 + er) * 128;
    if (j == i) {
#pragma unroll
      for (int nf = 0; nf < 4; ++nf) {
        int cb = wn * 64 + nf * 16 + lq * 4;
        *(f32x4*)(orow + cb) = *(const f32x4*)(oeb + cb);
      }
    } else {
#pragma unroll
      for (int nf = 0; nf < 4; ++nf) {
        int cb = wn * 64 + nf * 16 + lq * 4;
        f32x4 q4 = *(const f32x4*)(Qrow + cb);
        *(f32x4*)(orow + cb) = acc[mf][nf] + pc[nf] + q4;
      }
    }
  }
}

extern "C" void kernel_launch(void* const* d_in, const int* in_sizes, int n_in,
                              void* d_out, int out_size, void* d_ws, size_t ws_size,
                              hipStream_t stream) {
  const float* node = (const float*)d_in[0];
  const float* edge = (const float*)d_in[1];
  const float* Wn_w = (const float*)d_in[2];
  const float* Wn_b = (const float*)d_in[3];
  const float* Wh_w = (const float*)d_in[4];
  const float* Wh_b = (const float*)d_in[5];
  const float* We_w = (const float*)d_in[6];
  const float* We_b = (const float*)d_in[7];
  const float* Wn2_w = (const float*)d_in[8];
  const float* Wn2_b = (const float*)d_in[9];
  const float* We2_w = (const float*)d_in[10];
  const float* We2_b = (const float*)d_in[11];
  const float* attn_w = (const float*)d_in[12];
  const float* edge_w = (const float*)d_in[13];
  const float* edge_b = (const float*)d_in[14];
  const float* out_n_w = (const float*)d_in[15];
  const float* out_n_b = (const float*)d_in[16];
  const float* out_e_w = (const float*)d_in[17];
  const float* out_e_b = (const float*)d_in[18];

  float* out_node = (float*)d_out;            // 262144
  float* out_edge = ((float*)d_out) + 262144; // 33554432

  float* ws = (float*)d_ws;
  float* node_p = ws;                      // 262144
  float* Whh    = ws + 262144;             // 262144
  float* node_h = ws + 524288;             // 262144
  float* si     = ws + 786432;             // 8192
  float* sjv    = ws + 794624;             // 8192
  float* Pg     = ws + 802816;             // 131072
  float* Qg     = ws + 933888;             // 131072
  float* chg    = ws + 1064960;            // 128
  float* c0g    = ws + 1065088;            // 128
  short* Gt     = (short*)(ws + 1065216);  // 16384 shorts = 8192 floats
  short* Vbf    = (short*)(ws + 1073408);  // 2048 shorts = 1024 floats
  float* seg    = ws + 1074432;            // 2097152
  short* ebf    = (short*)(ws + 3171584);  // 33554432 shorts = 16777216 floats
  const bool big = ws_size >= (size_t)19948800 * 4;

  prep_kernel<<<129, 128, 0, stream>>>(We_w, We_b, attn_w, We2_w, We2_b, edge_w, edge_b,
                                       out_e_w, out_e_b, Vbf, chg, c0g, Gt);
  node_in_fused<<<256, 256, 0, stream>>>(node, Wn_w, Wn_b, Wh_w, Wh_b, attn_w, node_p, Whh,
                                         si, sjv);
  if (big)
    pass_a<true><<<1024, 256, 0, stream>>>(edge, Vbf, chg, ebf, seg);
  else
    pass_a<false><<<1024, 256, 0, stream>>>(edge, Vbf, chg, ebf, seg);
  attn_fused<<<1024, 256, 0, stream>>>(node_p, Whh, si, sjv, seg, node_h);
  node_out_pq<<<256, 256, 0, stream>>>(node_h, out_n_w, out_n_b, Wn2_w, Wn2_b, edge_w,
                                       out_e_w, out_node, Pg, Qg);
  if (big)
    edge_out_kernel<true><<<2048, 256, 0, stream>>>(edge, ebf, Gt, Pg, Qg, c0g, out_e_b,
                                                    out_edge);
  else
    edge_out_kernel<false><<<2048, 256, 0, stream>>>(edge, ebf, Gt, Pg, Qg, c0g, out_e_b,
                                                     out_edge);
}

// Round 6
// 170.962 us; speedup vs baseline: 1.1315x; 1.1315x over previous
//
#include <hip/hip_runtime.h>

#define Bb 4
#define Ll 256
#define NEG 0.2f

typedef __attribute__((ext_vector_type(8))) short short8;
typedef __attribute__((ext_vector_type(4))) float f32x4;
typedef __attribute__((ext_vector_type(4))) unsigned uint4v;

__device__ __forceinline__ float lrelu(float x) { return x >= 0.f ? x : NEG * x; }

__device__ __forceinline__ short f2bf(float x) {
  unsigned u = __builtin_bit_cast(unsigned, x);
  unsigned r = (u + 0x7FFFu + ((u >> 16) & 1u)) >> 16;
  return (short)r;
}

// pack two f32 -> u32 of 2 bf16 (round half up)
__device__ __forceinline__ unsigned pack2bf(float e, float o) {
  unsigned ue = __builtin_bit_cast(unsigned, e);
  unsigned uo = __builtin_bit_cast(unsigned, o);
  return ((ue + 0x8000u) >> 16) | ((uo + 0x8000u) & 0xFFFF0000u);
}

// ---------------- merged prep: blocks 0..127 -> Gt (linear bf16 [n][k]);
// block 128 -> Vbf (bf16 [16][128], rows 8..15 zero), ch(8), c0(128) ----------------
__global__ void prep_kernel(const float* We_w, const float* We_b, const float* attn_w,
                            const float* We2_w, const float* We2_b, const float* edge_w,
                            const float* edge_b, const float* out_e_w, const float* out_e_b,
                            short* Vbf, float* chg, float* c0g, short* Gt) {
  int blk = blockIdx.x;
  int t = threadIdx.x; // 128 threads
  if (blk < 128) {
    __shared__ float m2[128];
    int c = blk; // k index
    int h = t >> 4, e = t & 15;
    float s = 0.f;
    for (int d = 0; d < 16; ++d) s += We2_w[c * 128 + h * 16 + d] * edge_w[d * 16 + e];
    m2[t] = s;
    __syncthreads();
    float g = 0.f;
    for (int f = 0; f < 128; ++f) g += m2[f] * out_e_w[f * 128 + t];
    Gt[t * 128 + c] = f2bf(g);
  } else {
    __shared__ float b2e[128];
    const float* we = attn_w + 64;
    for (int idx = t; idx < 1024; idx += 128) {
      int c = idx >> 3, h = idx & 7;
      float s = 0.f;
      for (int d = 0; d < 16; ++d) s += We_w[c * 128 + h * 16 + d] * we[d];
      Vbf[h * 128 + c] = f2bf(s);
      Vbf[(h + 8) * 128 + c] = 0;
    }
    if (t < 8) {
      float s = 0.f;
      for (int d = 0; d < 16; ++d) s += We_b[t * 16 + d] * we[d];
      chg[t] = s;
    }
    {
      int h = t >> 4, e = t & 15;
      float s = 0.f;
      for (int d = 0; d < 16; ++d) s += We2_b[h * 16 + d] * edge_w[d * 16 + e];
      b2e[t] = s + edge_b[e];
    }
    __syncthreads();
    float s = out_e_b[t];
    for (int f = 0; f < 128; ++f) s += b2e[f] * out_e_w[f * 128 + t];
    c0g[t] = s;
  }
}

// ---------------- pack: edge fp32 -> ebf bf16, pure streaming ----------------
// 2048 blocks x 256 thr x 8 groups of 8 floats = 33.5M elements.
__global__ __launch_bounds__(256) void pack_kernel(const float* __restrict__ edge,
                                                   short* __restrict__ ebf) {
  long base = (long)blockIdx.x * 256 + threadIdx.x;
#pragma unroll
  for (int it = 0; it < 8; ++it) {
    long g = base + (long)it * 524288;
    const float4* src = reinterpret_cast<const float4*>(edge + g * 8);
    float4 f0 = src[0];
    float4 f1 = src[1];
    uint4v u;
    u.x = pack2bf(f0.x, f0.y);
    u.y = pack2bf(f0.z, f0.w);
    u.z = pack2bf(f1.x, f1.y);
    u.w = pack2bf(f1.z, f1.w);
    *(uint4v*)(ebf + g * 8) = u;
  }
}

// ---------------- node_in_fused: node_p = node@Wn + b; Whh; si; sj ----------------
__global__ __launch_bounds__(256) void node_in_fused(
    const float* __restrict__ node, const float* __restrict__ Wn_w,
    const float* __restrict__ Wn_b, const float* __restrict__ Wh_w,
    const float* __restrict__ Wh_b, const float* __restrict__ attn_w,
    float* __restrict__ node_p, float* __restrict__ Whh, float* __restrict__ si,
    float* __restrict__ sj) {
  __shared__ float a[4][256];
  __shared__ float np[4][256];
  int t = threadIdx.x;
  int row0 = blockIdx.x * 4;
  for (int q = t; q < 1024; q += 256) a[q >> 8][q & 255] = node[(long)row0 * 256 + q];
  __syncthreads();
  float acc[4];
  float bvv = Wn_b[t];
#pragma unroll
  for (int r = 0; r < 4; ++r) acc[r] = bvv;
  for (int k = 0; k < 256; ++k) {
    float w = Wn_w[k * 256 + t];
#pragma unroll
    for (int r = 0; r < 4; ++r) acc[r] += a[r][k] * w;
  }
#pragma unroll
  for (int r = 0; r < 4; ++r) {
    node_p[(long)(row0 + r) * 256 + t] = acc[r];
    np[r][t] = acc[r];
  }
  __syncthreads();
  int h = t >> 5, e = t & 31;
  float wb2 = Wh_b[e];
#pragma unroll
  for (int r = 0; r < 4; ++r) {
    float s = wb2;
    for (int d = 0; d < 32; ++d) s += np[r][h * 32 + d] * Wh_w[d * 32 + e];
    Whh[(long)(row0 + r) * 256 + t] = s;
  }
  if (t < 64) {
    int r = t >> 4, idx = t & 15, hh = idx & 7;
    const float* w = attn_w + (idx < 8 ? 0 : 32);
    float s = 0.f;
    for (int d = 0; d < 32; ++d) s += np[r][hh * 32 + d] * w[d];
    ((idx < 8) ? si : sj)[(long)(row0 + r) * 8 + hh] = s;
  }
}

// ---------------- attn_fused v3: se via MFMA from ebf slab + softmax + agg ----------------
template <bool UE>
__global__ __launch_bounds__(256) void attn_fused(
    const float* __restrict__ node_p, const float* __restrict__ Whh,
    const float* __restrict__ si, const float* __restrict__ sj,
    const short* __restrict__ ebf, const float* __restrict__ edge,
    const short* __restrict__ Vbf, const float* __restrict__ chg,
    float* __restrict__ node_h) {
  __shared__ float sjl[2048];
  __shared__ float sel[2048];
  __shared__ float pl[2048];
  __shared__ float sil[8];
  int t = threadIdx.x, bi = blockIdx.x;
  int b = bi >> 8, i = bi & 255;
  for (int q = t; q < 2048; q += 256) sjl[q] = sj[(long)b * 2048 + q];
  if (t < 8) sil[t] = si[(long)bi * 8 + t];

  // --- se phase (MFMA): se[j][h] for this slab's 256 rows ---
  {
    int l = t & 63, w = t >> 6;
    int lc = l & 15, lq = l >> 4;
    short8 vb[4];
#pragma unroll
    for (int ks = 0; ks < 4; ++ks) vb[ks] = *(const short8*)(Vbf + lc * 128 + ks * 32 + lq * 8);
    f32x4 acc[4];
#pragma unroll
    for (int mf = 0; mf < 4; ++mf) acc[mf] = (f32x4){0.f, 0.f, 0.f, 0.f};
#pragma unroll
    for (int mf = 0; mf < 4; ++mf) {
      int row = w * 64 + mf * 16 + lc;
#pragma unroll
      for (int ks = 0; ks < 4; ++ks) {
        short8 av;
        if constexpr (UE) {
          av = *(const short8*)(ebf + (long)bi * 32768 + row * 128 + ks * 32 + lq * 8);
        } else {
          const float* ap = edge + (long)bi * 32768 + row * 128 + ks * 32 + lq * 8;
          float4 f0 = *(const float4*)ap;
          float4 f1 = *(const float4*)(ap + 4);
          uint4v u;
          u.x = pack2bf(f0.x, f0.y);
          u.y = pack2bf(f0.z, f0.w);
          u.z = pack2bf(f1.x, f1.y);
          u.w = pack2bf(f1.z, f1.w);
          av = __builtin_bit_cast(short8, u);
        }
        acc[mf] = __builtin_amdgcn_mfma_f32_16x16x32_bf16(vb[ks], av, acc[mf], 0, 0, 0);
      }
    }
    if (lq < 2) {
      f32x4 chv = *(const f32x4*)(chg + lq * 4);
#pragma unroll
      for (int mf = 0; mf < 4; ++mf) {
        int row = w * 64 + mf * 16 + lc;
        f32x4 v = acc[mf] + chv;
        *(f32x4*)(&sel[row * 8 + lq * 4]) = v;
      }
    }
  }
  __syncthreads();

  // --- softmax ---
  int g = t >> 5, l32 = t & 31;
  float sc[8];
  float mx = -1e30f;
#pragma unroll
  for (int m = 0; m < 8; ++m) {
    int k = l32 + 32 * m;
    float v = -1e30f;
    if (k < 255) {
      int jj = k + (k >= i ? 1 : 0);
      v = sil[g] + sjl[jj * 8 + g] + sel[jj * 8 + g];
      v = lrelu(v);
    }
    sc[m] = v;
    mx = fmaxf(mx, v);
  }
#pragma unroll
  for (int d = 16; d >= 1; d >>= 1) mx = fmaxf(mx, __shfl_xor(mx, d));
  float sum = 0.f;
#pragma unroll
  for (int m = 0; m < 8; ++m) {
    int k = l32 + 32 * m;
    float e = (k < 255) ? __expf(sc[m] - mx) : 0.f;
    sc[m] = e;
    sum += e;
  }
#pragma unroll
  for (int d = 16; d >= 1; d >>= 1) sum += __shfl_xor(sum, d);
  float inv = 1.f / sum;
#pragma unroll
  for (int m = 0; m < 8; ++m) {
    int k = l32 + 32 * m;
    if (k < 255) pl[k * 8 + g] = sc[m] * inv;
  }
  __syncthreads();

  // --- agg ---
  int h = g;
  const float* wb = Whh + (long)b * 65536 + t;
  float acc0 = 0.f, acc1 = 0.f;
#pragma unroll 8
  for (int j = 0; j < 256; j += 2) {
    int k0 = (j == 0) ? 254 : (j - 1);
    int k1 = j;
    float w0 = (j == i) ? 0.f : pl[k0 * 8 + h];
    float w1 = (j + 1 == i) ? 0.f : pl[k1 * 8 + h];
    acc0 += w0 * wb[(long)j * 256];
    acc1 += w1 * wb[(long)(j + 1) * 256];
  }
  float acc = acc0 + acc1;
  float np = node_p[(long)bi * 256 + t];
  node_h[(long)bi * 256 + t] = np + lrelu(acc);
}

// ---------------- node_out_pq: out_node; node_p2; P/Q ----------------
__global__ __launch_bounds__(256) void node_out_pq(
    const float* __restrict__ node_h, const float* __restrict__ out_n_w,
    const float* __restrict__ out_n_b, const float* __restrict__ Wn2_w,
    const float* __restrict__ Wn2_b, const float* __restrict__ edge_w,
    const float* __restrict__ out_e_w, float* __restrict__ out_node,
    float* __restrict__ Pg, float* __restrict__ Qg) {
  __shared__ float a[4][256];
  __shared__ float b2[4][256];
  __shared__ float ninj[4][256];
  int t = threadIdx.x;
  int row0 = blockIdx.x * 4;
  for (int q = t; q < 1024; q += 256) a[q >> 8][q & 255] = node_h[(long)row0 * 256 + q];
  __syncthreads();
  float acc[4];
  float bv1 = out_n_b[t];
#pragma unroll
  for (int r = 0; r < 4; ++r) acc[r] = bv1;
  for (int k = 0; k < 256; ++k) {
    float w = out_n_w[k * 256 + t];
#pragma unroll
    for (int r = 0; r < 4; ++r) acc[r] += a[r][k] * w;
  }
#pragma unroll
  for (int r = 0; r < 4; ++r) {
    out_node[(long)(row0 + r) * 256 + t] = acc[r];
    b2[r][t] = acc[r];
  }
  __syncthreads();
  float acc2[4];
  float bv2 = Wn2_b[t];
#pragma unroll
  for (int r = 0; r < 4; ++r) acc2[r] = bv2;
  for (int k = 0; k < 256; ++k) {
    float w = Wn2_w[k * 256 + t];
#pragma unroll
    for (int r = 0; r < 4; ++r) acc2[r] += b2[r][k] * w;
  }
#pragma unroll
  for (int r = 0; r < 4; ++r) a[r][t] = acc2[r]; // node_p2
  __syncthreads();
  {
    int f = t & 127, h = f >> 4, e = f & 15;
    const float* w = edge_w + 256 + (t >> 7) * 512; // w_i / w_j
#pragma unroll
    for (int r = 0; r < 4; ++r) {
      float s = 0.f;
      for (int d = 0; d < 32; ++d) s += a[r][h * 32 + d] * w[d * 16 + e];
      ninj[r][t] = s;
    }
  }
  __syncthreads();
  {
    int o = t & 127;
    int half = (t >> 7) * 128;
#pragma unroll
    for (int r = 0; r < 4; ++r) {
      float s = 0.f;
      const float* src = ninj[r] + half;
      for (int f = 0; f < 128; ++f) s += src[f] * out_e_w[f * 128 + o];
      ((t < 128) ? Pg : Qg)[(long)(row0 + r) * 128 + o] = s;
    }
  }
}

// ---------------- pass C (MFMA, barrier-free streaming) ----------------
template <bool UE>
__global__ __launch_bounds__(256) void edge_out_kernel(
    const float* __restrict__ edge, const short* __restrict__ ebf,
    const short* __restrict__ Gt, const float* __restrict__ Pg,
    const float* __restrict__ Qg, const float* __restrict__ c0g,
    const float* __restrict__ oeb, float* __restrict__ out_edge) {
  int t = threadIdx.x;
  int l = t & 63, wid = t >> 6;
  int wm = wid >> 1, wn = wid & 1;
  int lc = l & 15, lq = l >> 4;

  long row0 = (long)blockIdx.x * 128;
  int b = (int)(row0 >> 16);
  int i = (int)((row0 >> 8) & 255);
  int j0 = (int)(row0 & 255);

  short8 bv[4][4];
#pragma unroll
  for (int ks = 0; ks < 4; ++ks)
#pragma unroll
    for (int nf = 0; nf < 4; ++nf)
      bv[ks][nf] = *(const short8*)(Gt + (wn * 64 + nf * 16 + lc) * 128 + ks * 32 + lq * 8);

  f32x4 acc[4][4];
#pragma unroll
  for (int mf = 0; mf < 4; ++mf)
#pragma unroll
    for (int nf = 0; nf < 4; ++nf) acc[mf][nf] = (f32x4){0.f, 0.f, 0.f, 0.f};

#pragma unroll
  for (int ks = 0; ks < 4; ++ks) {
    short8 av[4];
#pragma unroll
    for (int mf = 0; mf < 4; ++mf) {
      long row = row0 + wm * 64 + mf * 16 + lc;
      if constexpr (UE) {
        av[mf] = *(const short8*)(ebf + row * 128 + ks * 32 + lq * 8);
      } else {
        const float* ap = edge + row * 128 + ks * 32 + lq * 8;
        float4 f0 = *(const float4*)ap;
        float4 f1 = *(const float4*)(ap + 4);
        uint4v u;
        u.x = pack2bf(f0.x, f0.y);
        u.y = pack2bf(f0.z, f0.w);
        u.z = pack2bf(f1.x, f1.y);
        u.w = pack2bf(f1.z, f1.w);
        av[mf] = __builtin_bit_cast(short8, u);
      }
    }
#pragma unroll
    for (int mf = 0; mf < 4; ++mf)
#pragma unroll
      for (int nf = 0; nf < 4; ++nf)
        acc[mf][nf] =
            __builtin_amdgcn_mfma_f32_16x16x32_bf16(bv[ks][nf], av[mf], acc[mf][nf], 0, 0, 0);
  }

  f32x4 pc[4];
#pragma unroll
  for (int nf = 0; nf < 4; ++nf) {
    int cb = wn * 64 + nf * 16 + lq * 4;
    f32x4 p = *(const f32x4*)(Pg + ((long)(b * 256 + i)) * 128 + cb);
    f32x4 c0 = *(const f32x4*)(c0g + cb);
    pc[nf] = p + c0;
  }
#pragma unroll
  for (int mf = 0; mf < 4; ++mf) {
    int er = wm * 64 + mf * 16 + lc;
    int j = j0 + er;
    const float* Qrow = Qg + ((long)(b * 256 + j)) * 128;
    float* orow = out_edge + (row0 + er) * 128;
    if (j == i) {
#pragma unroll
      for (int nf = 0; nf < 4; ++nf) {
        int cb = wn * 64 + nf * 16 + lq * 4;
        f32x4 v = *(const f32x4*)(oeb + cb);
        __builtin_nontemporal_store(v, (f32x4*)(orow + cb));
      }
    } else {
#pragma unroll
      for (int nf = 0; nf < 4; ++nf) {
        int cb = wn * 64 + nf * 16 + lq * 4;
        f32x4 q4 = *(const f32x4*)(Qrow + cb);
        f32x4 v = acc[mf][nf] + pc[nf] + q4;
        __builtin_nontemporal_store(v, (f32x4*)(orow + cb));
      }
    }
  }
}

extern "C" void kernel_launch(void* const* d_in, const int* in_sizes, int n_in,
                              void* d_out, int out_size, void* d_ws, size_t ws_size,
                              hipStream_t stream) {
  const float* node = (const float*)d_in[0];
  const float* edge = (const float*)d_in[1];
  const float* Wn_w = (const float*)d_in[2];
  const float* Wn_b = (const float*)d_in[3];
  const float* Wh_w = (const float*)d_in[4];
  const float* Wh_b = (const float*)d_in[5];
  const float* We_w = (const float*)d_in[6];
  const float* We_b = (const float*)d_in[7];
  const float* Wn2_w = (const float*)d_in[8];
  const float* Wn2_b = (const float*)d_in[9];
  const float* We2_w = (const float*)d_in[10];
  const float* We2_b = (const float*)d_in[11];
  const float* attn_w = (const float*)d_in[12];
  const float* edge_w = (const float*)d_in[13];
  const float* edge_b = (const float*)d_in[14];
  const float* out_n_w = (const float*)d_in[15];
  const float* out_n_b = (const float*)d_in[16];
  const float* out_e_w = (const float*)d_in[17];
  const float* out_e_b = (const float*)d_in[18];

  float* out_node = (float*)d_out;            // 262144
  float* out_edge = ((float*)d_out) + 262144; // 33554432

  float* ws = (float*)d_ws;
  float* node_p = ws;                      // 262144
  float* Whh    = ws + 262144;             // 262144
  float* node_h = ws + 524288;             // 262144
  float* si     = ws + 786432;             // 8192
  float* sjv    = ws + 794624;             // 8192
  float* Pg     = ws + 802816;             // 131072
  float* Qg     = ws + 933888;             // 131072
  float* chg    = ws + 1064960;            // 128
  float* c0g    = ws + 1065088;            // 128
  short* Gt     = (short*)(ws + 1065216);  // 16384 shorts = 8192 floats
  short* Vbf    = (short*)(ws + 1073408);  // 2048 shorts = 1024 floats
  short* ebf    = (short*)(ws + 1074432);  // 33554432 shorts = 16777216 floats
  const bool big = ws_size >= (size_t)(1074432 + 16777216) * 4;

  prep_kernel<<<129, 128, 0, stream>>>(We_w, We_b, attn_w, We2_w, We2_b, edge_w, edge_b,
                                       out_e_w, out_e_b, Vbf, chg, c0g, Gt);
  node_in_fused<<<256, 256, 0, stream>>>(node, Wn_w, Wn_b, Wh_w, Wh_b, attn_w, node_p, Whh,
                                         si, sjv);
  if (big) {
    pack_kernel<<<2048, 256, 0, stream>>>(edge, ebf);
    attn_fused<true><<<1024, 256, 0, stream>>>(node_p, Whh, si, sjv, ebf, edge, Vbf, chg,
                                               node_h);
  } else {
    attn_fused<false><<<1024, 256, 0, stream>>>(node_p, Whh, si, sjv, ebf, edge, Vbf, chg,
                                                node_h);
  }
  node_out_pq<<<256, 256, 0, stream>>>(node_h, out_n_w, out_n_b, Wn2_w, Wn2_b, edge_w,
                                       out_e_w, out_node, Pg, Qg);
  if (big)
    edge_out_kernel<true><<<2048, 256, 0, stream>>>(edge, ebf, Gt, Pg, Qg, c0g, out_e_b,
                                                    out_edge);
  else
    edge_out_kernel<false><<<2048, 256, 0, stream>>>(edge, ebf, Gt, Pg, Qg, c0g, out_e_b,
                                                     out_edge);
}

// Round 7
// 170.739 us; speedup vs baseline: 1.1330x; 1.0013x over previous
//
#include <hip/hip_runtime.h>

#define Bb 4
#define Ll 256
#define NEG 0.2f

typedef __attribute__((ext_vector_type(8))) short short8;
typedef __attribute__((ext_vector_type(4))) float f32x4;
typedef __attribute__((ext_vector_type(4))) unsigned uint4v;

__device__ __forceinline__ float lrelu(float x) { return x >= 0.f ? x : NEG * x; }

__device__ __forceinline__ short f2bf(float x) {
  unsigned u = __builtin_bit_cast(unsigned, x);
  unsigned r = (u + 0x7FFFu + ((u >> 16) & 1u)) >> 16;
  return (short)r;
}

// pack two f32 -> u32 of 2 bf16 (round half up)
__device__ __forceinline__ unsigned pack2bf(float e, float o) {
  unsigned ue = __builtin_bit_cast(unsigned, e);
  unsigned uo = __builtin_bit_cast(unsigned, o);
  return ((ue + 0x8000u) >> 16) | ((uo + 0x8000u) & 0xFFFF0000u);
}

// ---------------- merged prep: blocks 0..127 -> Gt (linear bf16 [n][k]);
// block 128 -> Vbf (bf16 [16][128], rows 8..15 zero), ch(8), c0(128) ----------------
__global__ void prep_kernel(const float* We_w, const float* We_b, const float* attn_w,
                            const float* We2_w, const float* We2_b, const float* edge_w,
                            const float* edge_b, const float* out_e_w, const float* out_e_b,
                            short* Vbf, float* chg, float* c0g, short* Gt) {
  int blk = blockIdx.x;
  int t = threadIdx.x; // 128 threads
  if (blk < 128) {
    __shared__ float m2[128];
    int c = blk; // k index
    int h = t >> 4, e = t & 15;
    float s = 0.f;
    for (int d = 0; d < 16; ++d) s += We2_w[c * 128 + h * 16 + d] * edge_w[d * 16 + e];
    m2[t] = s;
    __syncthreads();
    float g = 0.f;
    for (int f = 0; f < 128; ++f) g += m2[f] * out_e_w[f * 128 + t];
    Gt[t * 128 + c] = f2bf(g);
  } else {
    __shared__ float b2e[128];
    const float* we = attn_w + 64;
    for (int idx = t; idx < 1024; idx += 128) {
      int c = idx >> 3, h = idx & 7;
      float s = 0.f;
      for (int d = 0; d < 16; ++d) s += We_w[c * 128 + h * 16 + d] * we[d];
      Vbf[h * 128 + c] = f2bf(s);
      Vbf[(h + 8) * 128 + c] = 0;
    }
    if (t < 8) {
      float s = 0.f;
      for (int d = 0; d < 16; ++d) s += We_b[t * 16 + d] * we[d];
      chg[t] = s;
    }
    {
      int h = t >> 4, e = t & 15;
      float s = 0.f;
      for (int d = 0; d < 16; ++d) s += We2_b[h * 16 + d] * edge_w[d * 16 + e];
      b2e[t] = s + edge_b[e];
    }
    __syncthreads();
    float s = out_e_b[t];
    for (int f = 0; f < 128; ++f) s += b2e[f] * out_e_w[f * 128 + t];
    c0g[t] = s;
  }
}

// ---------------- pack: edge fp32 -> ebf bf16, pure streaming ----------------
__global__ __launch_bounds__(256) void pack_kernel(const float* __restrict__ edge,
                                                   short* __restrict__ ebf) {
  long base = (long)blockIdx.x * 256 + threadIdx.x;
#pragma unroll
  for (int it = 0; it < 8; ++it) {
    long g = base + (long)it * 524288;
    const float4* src = reinterpret_cast<const float4*>(edge + g * 8);
    float4 f0 = src[0];
    float4 f1 = src[1];
    uint4v u;
    u.x = pack2bf(f0.x, f0.y);
    u.y = pack2bf(f0.z, f0.w);
    u.z = pack2bf(f1.x, f1.y);
    u.w = pack2bf(f1.z, f1.w);
    *(uint4v*)(ebf + g * 8) = u;
  }
}

// ---------------- node_in_fused: node_p = node@Wn + b; Whh; si; sj ----------------
__global__ __launch_bounds__(256) void node_in_fused(
    const float* __restrict__ node, const float* __restrict__ Wn_w,
    const float* __restrict__ Wn_b, const float* __restrict__ Wh_w,
    const float* __restrict__ Wh_b, const float* __restrict__ attn_w,
    float* __restrict__ node_p, float* __restrict__ Whh, float* __restrict__ si,
    float* __restrict__ sj) {
  __shared__ float a[4][256];
  __shared__ float np[4][256];
  int t = threadIdx.x;
  int row0 = blockIdx.x * 4;
  for (int q = t; q < 1024; q += 256) a[q >> 8][q & 255] = node[(long)row0 * 256 + q];
  __syncthreads();
  float acc[4];
  float bvv = Wn_b[t];
#pragma unroll
  for (int r = 0; r < 4; ++r) acc[r] = bvv;
  for (int k = 0; k < 256; ++k) {
    float w = Wn_w[k * 256 + t];
#pragma unroll
    for (int r = 0; r < 4; ++r) acc[r] += a[r][k] * w;
  }
#pragma unroll
  for (int r = 0; r < 4; ++r) {
    node_p[(long)(row0 + r) * 256 + t] = acc[r];
    np[r][t] = acc[r];
  }
  __syncthreads();
  int h = t >> 5, e = t & 31;
  float wb2 = Wh_b[e];
#pragma unroll
  for (int r = 0; r < 4; ++r) {
    float s = wb2;
    for (int d = 0; d < 32; ++d) s += np[r][h * 32 + d] * Wh_w[d * 32 + e];
    Whh[(long)(row0 + r) * 256 + t] = s;
  }
  if (t < 64) {
    int r = t >> 4, idx = t & 15, hh = idx & 7;
    const float* w = attn_w + (idx < 8 ? 0 : 32);
    float s = 0.f;
    for (int d = 0; d < 32; ++d) s += np[r][hh * 32 + d] * w[d];
    ((idx < 8) ? si : sj)[(long)(row0 + r) * 8 + hh] = s;
  }
}

// ---------------- attn_fused v4: se via MFMA (all loads upfront) + softmax + agg --------
template <bool UE>
__global__ __launch_bounds__(256) void attn_fused(
    const float* __restrict__ node_p, const float* __restrict__ Whh,
    const float* __restrict__ si, const float* __restrict__ sj,
    const short* __restrict__ ebf, const float* __restrict__ edge,
    const short* __restrict__ Vbf, const float* __restrict__ chg,
    float* __restrict__ node_h) {
  __shared__ float sjl[2048];
  __shared__ float sel[2048];
  __shared__ float pl[2048];
  __shared__ float sil[8];
  int t = threadIdx.x, bi = blockIdx.x;
  int b = bi >> 8, i = bi & 255;
  for (int q = t; q < 2048; q += 256) sjl[q] = sj[(long)b * 2048 + q];
  if (t < 8) sil[t] = si[(long)bi * 8 + t];

  // --- se phase (MFMA): all 16 A-fragment loads in flight before any MFMA ---
  {
    int l = t & 63, w = t >> 6;
    int lc = l & 15, lq = l >> 4;
    short8 vb[4];
#pragma unroll
    for (int ks = 0; ks < 4; ++ks) vb[ks] = *(const short8*)(Vbf + lc * 128 + ks * 32 + lq * 8);

    short8 av[4][4]; // [mf][ks]
#pragma unroll
    for (int mf = 0; mf < 4; ++mf) {
      int row = w * 64 + mf * 16 + lc;
#pragma unroll
      for (int ks = 0; ks < 4; ++ks) {
        if constexpr (UE) {
          av[mf][ks] = *(const short8*)(ebf + (long)bi * 32768 + row * 128 + ks * 32 + lq * 8);
        } else {
          const float* ap = edge + (long)bi * 32768 + row * 128 + ks * 32 + lq * 8;
          float4 f0 = *(const float4*)ap;
          float4 f1 = *(const float4*)(ap + 4);
          uint4v u;
          u.x = pack2bf(f0.x, f0.y);
          u.y = pack2bf(f0.z, f0.w);
          u.z = pack2bf(f1.x, f1.y);
          u.w = pack2bf(f1.z, f1.w);
          av[mf][ks] = __builtin_bit_cast(short8, u);
        }
      }
    }
    f32x4 acc[4];
#pragma unroll
    for (int mf = 0; mf < 4; ++mf) acc[mf] = (f32x4){0.f, 0.f, 0.f, 0.f};
#pragma unroll
    for (int mf = 0; mf < 4; ++mf)
#pragma unroll
      for (int ks = 0; ks < 4; ++ks)
        acc[mf] = __builtin_amdgcn_mfma_f32_16x16x32_bf16(vb[ks], av[mf][ks], acc[mf], 0, 0, 0);
    if (lq < 2) {
      f32x4 chv = *(const f32x4*)(chg + lq * 4);
#pragma unroll
      for (int mf = 0; mf < 4; ++mf) {
        int row = w * 64 + mf * 16 + lc;
        f32x4 v = acc[mf] + chv;
        *(f32x4*)(&sel[row * 8 + lq * 4]) = v;
      }
    }
  }
  __syncthreads();

  // --- softmax ---
  int g = t >> 5, l32 = t & 31;
  float sc[8];
  float mx = -1e30f;
#pragma unroll
  for (int m = 0; m < 8; ++m) {
    int k = l32 + 32 * m;
    float v = -1e30f;
    if (k < 255) {
      int jj = k + (k >= i ? 1 : 0);
      v = sil[g] + sjl[jj * 8 + g] + sel[jj * 8 + g];
      v = lrelu(v);
    }
    sc[m] = v;
    mx = fmaxf(mx, v);
  }
#pragma unroll
  for (int d = 16; d >= 1; d >>= 1) mx = fmaxf(mx, __shfl_xor(mx, d));
  float sum = 0.f;
#pragma unroll
  for (int m = 0; m < 8; ++m) {
    int k = l32 + 32 * m;
    float e = (k < 255) ? __expf(sc[m] - mx) : 0.f;
    sc[m] = e;
    sum += e;
  }
#pragma unroll
  for (int d = 16; d >= 1; d >>= 1) sum += __shfl_xor(sum, d);
  float inv = 1.f / sum;
#pragma unroll
  for (int m = 0; m < 8; ++m) {
    int k = l32 + 32 * m;
    if (k < 255) pl[k * 8 + g] = sc[m] * inv;
  }
  __syncthreads();

  // --- agg ---
  int h = g;
  const float* wb = Whh + (long)b * 65536 + t;
  float acc0 = 0.f, acc1 = 0.f;
#pragma unroll 8
  for (int j = 0; j < 256; j += 2) {
    int k0 = (j == 0) ? 254 : (j - 1);
    int k1 = j;
    float w0 = (j == i) ? 0.f : pl[k0 * 8 + h];
    float w1 = (j + 1 == i) ? 0.f : pl[k1 * 8 + h];
    acc0 += w0 * wb[(long)j * 256];
    acc1 += w1 * wb[(long)(j + 1) * 256];
  }
  float acc = acc0 + acc1;
  float np = node_p[(long)bi * 256 + t];
  node_h[(long)bi * 256 + t] = np + lrelu(acc);
}

// ---------------- node_out_pq: out_node; node_p2; P/Q ----------------
__global__ __launch_bounds__(256) void node_out_pq(
    const float* __restrict__ node_h, const float* __restrict__ out_n_w,
    const float* __restrict__ out_n_b, const float* __restrict__ Wn2_w,
    const float* __restrict__ Wn2_b, const float* __restrict__ edge_w,
    const float* __restrict__ out_e_w, float* __restrict__ out_node,
    float* __restrict__ Pg, float* __restrict__ Qg) {
  __shared__ float a[4][256];
  __shared__ float b2[4][256];
  __shared__ float ninj[4][256];
  int t = threadIdx.x;
  int row0 = blockIdx.x * 4;
  for (int q = t; q < 1024; q += 256) a[q >> 8][q & 255] = node_h[(long)row0 * 256 + q];
  __syncthreads();
  float acc[4];
  float bv1 = out_n_b[t];
#pragma unroll
  for (int r = 0; r < 4; ++r) acc[r] = bv1;
  for (int k = 0; k < 256; ++k) {
    float w = out_n_w[k * 256 + t];
#pragma unroll
    for (int r = 0; r < 4; ++r) acc[r] += a[r][k] * w;
  }
#pragma unroll
  for (int r = 0; r < 4; ++r) {
    out_node[(long)(row0 + r) * 256 + t] = acc[r];
    b2[r][t] = acc[r];
  }
  __syncthreads();
  float acc2[4];
  float bv2 = Wn2_b[t];
#pragma unroll
  for (int r = 0; r < 4; ++r) acc2[r] = bv2;
  for (int k = 0; k < 256; ++k) {
    float w = Wn2_w[k * 256 + t];
#pragma unroll
    for (int r = 0; r < 4; ++r) acc2[r] += b2[r][k] * w;
  }
#pragma unroll
  for (int r = 0; r < 4; ++r) a[r][t] = acc2[r]; // node_p2
  __syncthreads();
  {
    int f = t & 127, h = f >> 4, e = f & 15;
    const float* w = edge_w + 256 + (t >> 7) * 512; // w_i / w_j
#pragma unroll
    for (int r = 0; r < 4; ++r) {
      float s = 0.f;
      for (int d = 0; d < 32; ++d) s += a[r][h * 32 + d] * w[d * 16 + e];
      ninj[r][t] = s;
    }
  }
  __syncthreads();
  {
    int o = t & 127;
    int half = (t >> 7) * 128;
#pragma unroll
    for (int r = 0; r < 4; ++r) {
      float s = 0.f;
      const float* src = ninj[r] + half;
      for (int f = 0; f < 128; ++f) s += src[f] * out_e_w[f * 128 + o];
      ((t < 128) ? Pg : Qg)[(long)(row0 + r) * 128 + o] = s;
    }
  }
}

// ---------------- pass C (MFMA, all A-loads upfront) ----------------
template <bool UE>
__global__ __launch_bounds__(256, 2) void edge_out_kernel(
    const float* __restrict__ edge, const short* __restrict__ ebf,
    const short* __restrict__ Gt, const float* __restrict__ Pg,
    const float* __restrict__ Qg, const float* __restrict__ c0g,
    const float* __restrict__ oeb, float* __restrict__ out_edge) {
  int t = threadIdx.x;
  int l = t & 63, wid = t >> 6;
  int wm = wid >> 1, wn = wid & 1;
  int lc = l & 15, lq = l >> 4;

  long row0 = (long)blockIdx.x * 128;
  int b = (int)(row0 >> 16);
  int i = (int)((row0 >> 8) & 255);
  int j0 = (int)(row0 & 255);

  // all 16 A-fragments in flight first (64 VGPR), then B, then MFMA
  short8 av[4][4]; // [ks][mf]
#pragma unroll
  for (int ks = 0; ks < 4; ++ks)
#pragma unroll
    for (int mf = 0; mf < 4; ++mf) {
      long row = row0 + wm * 64 + mf * 16 + lc;
      if constexpr (UE) {
        av[ks][mf] = *(const short8*)(ebf + row * 128 + ks * 32 + lq * 8);
      } else {
        const float* ap = edge + row * 128 + ks * 32 + lq * 8;
        float4 f0 = *(const float4*)ap;
        float4 f1 = *(const float4*)(ap + 4);
        uint4v u;
        u.x = pack2bf(f0.x, f0.y);
        u.y = pack2bf(f0.z, f0.w);
        u.z = pack2bf(f1.x, f1.y);
        u.w = pack2bf(f1.z, f1.w);
        av[ks][mf] = __builtin_bit_cast(short8, u);
      }
    }

  short8 bv[4][4];
#pragma unroll
  for (int ks = 0; ks < 4; ++ks)
#pragma unroll
    for (int nf = 0; nf < 4; ++nf)
      bv[ks][nf] = *(const short8*)(Gt + (wn * 64 + nf * 16 + lc) * 128 + ks * 32 + lq * 8);

  f32x4 acc[4][4];
#pragma unroll
  for (int mf = 0; mf < 4; ++mf)
#pragma unroll
    for (int nf = 0; nf < 4; ++nf) acc[mf][nf] = (f32x4){0.f, 0.f, 0.f, 0.f};

#pragma unroll
  for (int ks = 0; ks < 4; ++ks)
#pragma unroll
    for (int mf = 0; mf < 4; ++mf)
#pragma unroll
      for (int nf = 0; nf < 4; ++nf)
        acc[mf][nf] =
            __builtin_amdgcn_mfma_f32_16x16x32_bf16(bv[ks][nf], av[ks][mf], acc[mf][nf], 0, 0, 0);

  f32x4 pc[4];
#pragma unroll
  for (int nf = 0; nf < 4; ++nf) {
    int cb = wn * 64 + nf * 16 + lq * 4;
    f32x4 p = *(const f32x4*)(Pg + ((long)(b * 256 + i)) * 128 + cb);
    f32x4 c0 = *(const f32x4*)(c0g + cb);
    pc[nf] = p + c0;
  }
#pragma unroll
  for (int mf = 0; mf < 4; ++mf) {
    int er = wm * 64 + mf * 16 + lc;
    int j = j0 + er;
    const float* Qrow = Qg + ((long)(b * 256 + j)) * 128;
    float* orow = out_edge + (row0 + er) * 128;
    if (j == i) {
#pragma unroll
      for (int nf = 0; nf < 4; ++nf) {
        int cb = wn * 64 + nf * 16 + lq * 4;
        f32x4 v = *(const f32x4*)(oeb + cb);
        __builtin_nontemporal_store(v, (f32x4*)(orow + cb));
      }
    } else {
#pragma unroll
      for (int nf = 0; nf < 4; ++nf) {
        int cb = wn * 64 + nf * 16 + lq * 4;
        f32x4 q4 = *(const f32x4*)(Qrow + cb);
        f32x4 v = acc[mf][nf] + pc[nf] + q4;
        __builtin_nontemporal_store(v, (f32x4*)(orow + cb));
      }
    }
  }
}

extern "C" void kernel_launch(void* const* d_in, const int* in_sizes, int n_in,
                              void* d_out, int out_size, void* d_ws, size_t ws_size,
                              hipStream_t stream) {
  const float* node = (const float*)d_in[0];
  const float* edge = (const float*)d_in[1];
  const float* Wn_w = (const float*)d_in[2];
  const float* Wn_b = (const float*)d_in[3];
  const float* Wh_w = (const float*)d_in[4];
  const float* Wh_b = (const float*)d_in[5];
  const float* We_w = (const float*)d_in[6];
  const float* We_b = (const float*)d_in[7];
  const float* Wn2_w = (const float*)d_in[8];
  const float* Wn2_b = (const float*)d_in[9];
  const float* We2_w = (const float*)d_in[10];
  const float* We2_b = (const float*)d_in[11];
  const float* attn_w = (const float*)d_in[12];
  const float* edge_w = (const float*)d_in[13];
  const float* edge_b = (const float*)d_in[14];
  const float* out_n_w = (const float*)d_in[15];
  const float* out_n_b = (const float*)d_in[16];
  const float* out_e_w = (const float*)d_in[17];
  const float* out_e_b = (const float*)d_in[18];

  float* out_node = (float*)d_out;            // 262144
  float* out_edge = ((float*)d_out) + 262144; // 33554432

  float* ws = (float*)d_ws;
  float* node_p = ws;                      // 262144
  float* Whh    = ws + 262144;             // 262144
  float* node_h = ws + 524288;             // 262144
  float* si     = ws + 786432;             // 8192
  float* sjv    = ws + 794624;             // 8192
  float* Pg     = ws + 802816;             // 131072
  float* Qg     = ws + 933888;             // 131072
  float* chg    = ws + 1064960;            // 128
  float* c0g    = ws + 1065088;            // 128
  short* Gt     = (short*)(ws + 1065216);  // 16384 shorts = 8192 floats
  short* Vbf    = (short*)(ws + 1073408);  // 2048 shorts = 1024 floats
  short* ebf    = (short*)(ws + 1074432);  // 33554432 shorts = 16777216 floats
  const bool big = ws_size >= (size_t)(1074432 + 16777216) * 4;

  prep_kernel<<<129, 128, 0, stream>>>(We_w, We_b, attn_w, We2_w, We2_b, edge_w, edge_b,
                                       out_e_w, out_e_b, Vbf, chg, c0g, Gt);
  node_in_fused<<<256, 256, 0, stream>>>(node, Wn_w, Wn_b, Wh_w, Wh_b, attn_w, node_p, Whh,
                                         si, sjv);
  if (big) {
    pack_kernel<<<2048, 256, 0, stream>>>(edge, ebf);
    attn_fused<true><<<1024, 256, 0, stream>>>(node_p, Whh, si, sjv, ebf, edge, Vbf, chg,
                                               node_h);
  } else {
    attn_fused<false><<<1024, 256, 0, stream>>>(node_p, Whh, si, sjv, ebf, edge, Vbf, chg,
                                                node_h);
  }
  node_out_pq<<<256, 256, 0, stream>>>(node_h, out_n_w, out_n_b, Wn2_w, Wn2_b, edge_w,
                                       out_e_w, out_node, Pg, Qg);
  if (big)
    edge_out_kernel<true><<<2048, 256, 0, stream>>>(edge, ebf, Gt, Pg, Qg, c0g, out_e_b,
                                                    out_edge);
  else
    edge_out_kernel<false><<<2048, 256, 0, stream>>>(edge, ebf, Gt, Pg, Qg, c0g, out_e_b,
                                                     out_edge);
}